// Round 4
// baseline (333.993 us; speedup 1.0000x reference)
//
#include <hip/hip_runtime.h>
#include <hip/hip_bf16.h>

typedef __attribute__((ext_vector_type(8))) short short8;
typedef __attribute__((ext_vector_type(4))) float floatx4;
typedef __attribute__((ext_vector_type(16))) float floatx16;

__device__ inline unsigned short f2bf(float f) {
    unsigned int u = __float_as_uint(f);
    u += 0x7fffu + ((u >> 16) & 1u);           // round-to-nearest-even
    return (unsigned short)(u >> 16);
}

__device__ inline unsigned int pk_bf16(float lo, float hi) {
    __hip_bfloat162 h = __float22bfloat162_rn(float2{lo, hi});
    unsigned int u;
    __builtin_memcpy(&u, &h, 4);
    return u;
}

// ---------------- merged cast fp32 -> bf16 (all 5 tensors, one launch) -----
// Wq is pre-scaled by scale*log2(e) so flash computes exp2(q.k) directly.
__global__ void cast_all_kernel(const float* __restrict__ x,
                                const float* __restrict__ wq,
                                const float* __restrict__ wk,
                                const float* __restrict__ wv,
                                const float* __restrict__ wo,
                                unsigned short* __restrict__ xb,
                                unsigned short* __restrict__ wqkb,
                                unsigned short* __restrict__ wvb,
                                unsigned short* __restrict__ wob) {
    const float C2 = 0.08838834764831845f * 1.4426950408889634f;
    int bid = blockIdx.x;
    const float* src;
    unsigned short* dst;
    int base;
    float sc = 1.0f;
    if (bid < 8192)       { src = x;  dst = xb;             base = bid; }
    else if (bid < 12288) { src = wq; dst = wqkb;           base = bid - 8192; sc = C2; }
    else if (bid < 14336) { src = wk; dst = wqkb + 4194304; base = bid - 12288; }
    else if (bid < 16384) { src = wv; dst = wvb;            base = bid - 14336; }
    else                  { src = wo; dst = wob;            base = bid - 16384; }
    int i = base * 256 + threadIdx.x;   // float4 units
    float4 v = ((const float4*)src)[i];
    ushort4 o;
    o.x = f2bf(v.x * sc); o.y = f2bf(v.y * sc);
    o.z = f2bf(v.z * sc); o.w = f2bf(v.w * sc);
    ((ushort4*)dst)[i] = o;
}

// ---------------- BK=64 gemm core (device inline) -------------------------
// C[m,n] = sum_k A[m,k]*B[n,k]; 128x128 tile, BK=64, 32 MFMA per barrier
// pair. LDS tiles 128x64 with XOR-chunk swizzle: row R, global k-chunk j
// (8 elems) stored at slot j^(R&7) -> all fragment reads 2-way/bank = free.
template <int OUT_BF16>
__device__ __forceinline__ void gemm_bt64_body(
        const unsigned short* __restrict__ A,
        const unsigned short* __restrict__ B,
        void* __restrict__ Cp, int K, int ldc, int m0, int n0,
        unsigned short* sA, unsigned short* sB) {
    const int tid  = threadIdx.x;
    const int wave = tid >> 6;
    const int lane = tid & 63;
    const int l16  = lane & 15;
    const int lq   = lane >> 4;
    const int wm   = (wave >> 1) * 64;
    const int wn   = (wave & 1) * 64;

    floatx4 acc[4][4] = {};

    // staging: chunk c = wave*4+i covers rows c*8..c*8+7 (full 64 cols)
    // lane l -> row c*8 + (l>>3), slot l&7, global chunk (l&7)^(row&7)
    const unsigned short* gA[4];
    const unsigned short* gB[4];
#pragma unroll
    for (int i = 0; i < 4; i++) {
        int c   = wave * 4 + i;
        int row = c * 8 + (lane >> 3);
        int chs = (lane & 7) ^ (row & 7);
        gA[i] = A + (size_t)(m0 + row) * K + chs * 8;
        gB[i] = B + (size_t)(n0 + row) * K + chs * 8;
    }

    for (int k0 = 0; k0 < K; k0 += 64) {
        __syncthreads();
#pragma unroll
        for (int i = 0; i < 4; i++) {
            int c = wave * 4 + i;
            __builtin_amdgcn_global_load_lds(
                (const __attribute__((address_space(1))) void*)gA[i],
                (__attribute__((address_space(3))) void*)(sA + c * 512), 16, 0, 0);
            gA[i] += 64;
            __builtin_amdgcn_global_load_lds(
                (const __attribute__((address_space(1))) void*)gB[i],
                (__attribute__((address_space(3))) void*)(sB + c * 512), 16, 0, 0);
            gB[i] += 64;
        }
        __syncthreads();

        short8 af[2][4], bfr[2][4];
#pragma unroll
        for (int ks = 0; ks < 2; ks++) {
            int slot = (ks * 4 + lq) ^ (l16 & 7);   // row&7 == l16&7 (wm,mb mult of 8)
#pragma unroll
            for (int mb = 0; mb < 4; mb++)
                af[ks][mb] = *(const short8*)(sA + (wm + mb * 16 + l16) * 64 + slot * 8);
#pragma unroll
            for (int nb = 0; nb < 4; nb++)
                bfr[ks][nb] = *(const short8*)(sB + (wn + nb * 16 + l16) * 64 + slot * 8);
        }
#pragma unroll
        for (int ks = 0; ks < 2; ks++)
#pragma unroll
            for (int mb = 0; mb < 4; mb++)
#pragma unroll
                for (int nb = 0; nb < 4; nb++)
                    acc[mb][nb] = __builtin_amdgcn_mfma_f32_16x16x32_bf16(
                        af[ks][mb], bfr[ks][nb], acc[mb][nb], 0, 0, 0);
    }

#pragma unroll
    for (int mb = 0; mb < 4; mb++)
#pragma unroll
        for (int nb = 0; nb < 4; nb++)
#pragma unroll
            for (int r = 0; r < 4; r++) {
                int row = m0 + wm + mb * 16 + lq * 4 + r;
                int col = n0 + wn + nb * 16 + l16;
                if (OUT_BF16)
                    ((unsigned short*)Cp)[(size_t)row * ldc + col] = f2bf(acc[mb][nb][r]);
                else
                    ((float*)Cp)[(size_t)row * ldc + col] = acc[mb][nb][r];
            }
}

// ---------------- merged QK + Vt gemm (one dispatch, 1024 blocks) ----------
__global__ __launch_bounds__(256) void gemm_qkv_kernel(
        const unsigned short* __restrict__ x_bf,
        const unsigned short* __restrict__ Wqk,
        const unsigned short* __restrict__ Wv,
        unsigned short* __restrict__ QKb,
        unsigned short* __restrict__ Vtb) {
    __shared__ __align__(16) unsigned short sA[128 * 64];
    __shared__ __align__(16) unsigned short sB[128 * 64];
    const int bid = blockIdx.x;
    if (bid < 768) {
        gemm_bt64_body<1>(x_bf, Wqk, QKb, 2048, 3072,
                          (bid / 24) * 128, (bid % 24) * 128, sA, sB);
    } else {
        int t = bid - 768;
        gemm_bt64_body<1>(Wv, x_bf, Vtb, 2048, 4096,
                          (t / 32) * 128, (t % 32) * 128, sA, sB);
    }
}

// ---------------- O-proj gemm (fp32 out) ----------------
__global__ __launch_bounds__(256) void gemm_o_kernel(
        const unsigned short* __restrict__ A,
        const unsigned short* __restrict__ B,
        float* __restrict__ C) {
    __shared__ __align__(16) unsigned short sA[128 * 64];
    __shared__ __align__(16) unsigned short sB[128 * 64];
    gemm_bt64_body<0>(A, B, C, 2048, 2048,
                      blockIdx.y * 128, blockIdx.x * 128, sA, sB);
}

// ---------------- flash attention v5: 32x32x16 MFMA + in-register P --------
// 4 waves = 4 q-slices (32 q-rows = one 32x32 MFMA col-block each), all 64
// keys per wave. Changes vs v4:
//  - mfma_f32_32x32x16_bf16 for QK and PV: same FLOPs, half the instrs,
//    ~17% fewer MFMA cycles (8.07 vs 9.7 cyc per 32K FLOP)
//  - P never touches LDS: QK C-layout (col=q=lane&31, row-keys
//    (reg&3)+8*(reg>>2)+4*hi) regrouped to PV B-frags (same q, 8-key
//    k-slices) via one __shfl_xor(.,32) half-exchange per word.
//    Removes 8 b64 writes + 4 b128 reads + BOTH lgkmcnt(0) chain stalls/kt.
//  - LDS 64KB (sP deleted): sK[2][64x128] + sV[2][128x64], same swizzles.
__global__ __launch_bounds__(256, 2) void flash_kernel(
        const unsigned short* __restrict__ QK,
        const unsigned short* __restrict__ Vt,
        unsigned short* __restrict__ O) {
    // layout (ushorts): sK[2][8192] @0, sV[2][8192] @16384
    __shared__ __align__(16) unsigned short smem[32768];

    const int tid  = threadIdx.x;
    const int wave = tid >> 6;
    const int lane = tid & 63;
    const int l31  = lane & 31;
    const int hi   = lane >> 5;
    const int qt   = blockIdx.x;          // 0..15 (128 tokens each)
    const int bh   = blockIdx.y;
    const int b    = bh >> 4;
    const int h    = bh & 15;
    const int kvh  = h >> 1;
    const size_t tokbase = (size_t)b * 2048 + qt * 128 + wave * 32;

    // Q fragments (B-operand): q = tokbase + l31, k-slice hi*8 of each 16-d
    // step -> 8 x short8 = 32 VGPR, loaded once.
    short8 qf[8];
    {
        const unsigned short* qp =
            QK + (tokbase + l31) * 3072 + h * 128 + hi * 8;
#pragma unroll
        for (int ks = 0; ks < 8; ks++) qf[ks] = *(const short8*)(qp + ks * 16);
    }

    // staging pointers: wave handles K segs / V segs {wave*4 .. wave*4+3}
    // (identical to v4; layouts unchanged)
    const unsigned short* gKe =
        QK + ((size_t)b * 2048 + wave * 16 + (lane >> 4)) * 3072 + 2048 + kvh * 128 +
        ((lane & 15) ^ (lane >> 4)) * 8;
    const unsigned short* gKo =
        QK + ((size_t)b * 2048 + wave * 16 + 4 + (lane >> 4)) * 3072 + 2048 + kvh * 128 +
        ((lane & 15) ^ ((lane >> 4) + 4)) * 8;
    const unsigned short* gV0 =
        Vt + (size_t)(kvh * 128 + wave * 32 + (lane >> 3)) * 4096 +
        (size_t)b * 2048 + ((lane & 7) ^ (lane >> 3)) * 8;

#define STAGE_KT(sKd, sVd)                                                     \
    do {                                                                       \
        _Pragma("unroll")                                                      \
        for (int i = 0; i < 4; i++) {                                          \
            const unsigned short* gk =                                         \
                ((i & 1) ? gKo : gKe) + (i >> 1) * 24576;                      \
            __builtin_amdgcn_global_load_lds(                                  \
                (const __attribute__((address_space(1))) void*)gk,             \
                (__attribute__((address_space(3))) void*)((sKd) +              \
                                                          (wave * 4 + i) * 512),\
                16, 0, 0);                                                     \
            __builtin_amdgcn_global_load_lds(                                  \
                (const __attribute__((address_space(1))) void*)(gV0 +          \
                                                               i * 32768),     \
                (__attribute__((address_space(3))) void*)((sVd) +              \
                                                          (wave * 4 + i) * 512),\
                16, 0, 0);                                                     \
        }                                                                      \
        gKe += 196608; gKo += 196608; gV0 += 64;                               \
    } while (0)

    floatx16 oacc[4] = {};     // 4 d-blocks x 16 f32 = 64 acc regs
    float l_run = 0.0f;        // this lane's 32-of-64 keys; merged via xor(32)

    // prologue: stage tile 0, drain, barrier
    STAGE_KT(smem, smem + 16384);
    asm volatile("s_waitcnt vmcnt(0)" ::: "memory");
    __builtin_amdgcn_s_barrier();
    asm volatile("" ::: "memory");

    for (int kt = 0; kt < 32; kt++) {
        const int cur = kt & 1;
        const unsigned short* sKc = smem + cur * 8192;
        const unsigned short* sVc = smem + 16384 + cur * 8192;
        if (kt < 31) {
            unsigned short* sKn = smem + (cur ^ 1) * 8192;
            unsigned short* sVn = smem + 16384 + (cur ^ 1) * 8192;
            STAGE_KT(sKn, sVn);          // latency hides under this kt's compute
        }

#pragma unroll
        for (int kb = 0; kb < 2; kb++) {
            // ---- QK^T: 8 x mfma 32x32x16 (A=K rows=keys, B=Q cols=q) ----
            floatx16 sacc = {};
#pragma unroll
            for (int ks = 0; ks < 8; ks++) {
                short8 kf = *(const short8*)(
                    sKc + (kb * 32 + l31) * 128 +
                    (((ks * 2 + hi) ^ (l31 & 7)) * 8));
                sacc = __builtin_amdgcn_mfma_f32_32x32x16_bf16(
                    kf, qf[ks], sacc, 0, 0, 0);
            }

            // ---- softmax: lane holds keys kb*32 + 8g+4*hi+{0..3}, g=0..3 --
            float p[16];
#pragma unroll
            for (int r = 0; r < 16; r++) {
                p[r] = __builtin_exp2f(sacc[r]);
                l_run += p[r];
            }
            // pack per group g: word0 = keys {0,1}, word1 = {2,3} of group
            unsigned int pw0[4], pw1[4];
#pragma unroll
            for (int g = 0; g < 4; g++) {
                pw0[g] = pk_bf16(p[4 * g], p[4 * g + 1]);
                pw1[g] = pk_bf16(p[4 * g + 2], p[4 * g + 3]);
            }

            // ---- PV per 16-key step j (global kstep kj = kb*2+j) ----
            // B-frag lane (q,hi) needs keys 16j+8*hi+{0..7}. Half-exchange:
            // lane sends its group (hi ? 2j : 2j+1) word, receives partner's.
#pragma unroll
            for (int j = 0; j < 2; j++) {
                unsigned int s0 = hi ? pw0[2 * j] : pw0[2 * j + 1];
                unsigned int s1 = hi ? pw1[2 * j] : pw1[2 * j + 1];
                unsigned int r0 = __shfl_xor(s0, 32);
                unsigned int r1 = __shfl_xor(s1, 32);
                union { unsigned int w[4]; short8 s; } pu;
                pu.w[0] = hi ? r0 : pw0[2 * j];        // keys +0,1
                pu.w[1] = hi ? r1 : pw1[2 * j];        // keys +2,3
                pu.w[2] = hi ? pw0[2 * j + 1] : r0;    // keys +4,5
                pu.w[3] = hi ? pw1[2 * j + 1] : r1;    // keys +6,7
                short8 pfr = pu.s;
                const int kj = kb * 2 + j;
                __builtin_amdgcn_s_setprio(1);
#pragma unroll
                for (int db = 0; db < 4; db++) {
                    short8 vf = *(const short8*)(
                        sVc + (db * 32 + l31) * 64 +
                        (((kj * 2 + hi) ^ (l31 & 7)) * 8));
                    oacc[db] = __builtin_amdgcn_mfma_f32_32x32x16_bf16(
                        vf, pfr, oacc[db], 0, 0, 0);
                }
                __builtin_amdgcn_s_setprio(0);
            }
        }

        // end of phase: drain staging issued this kt, then barrier
        asm volatile("s_waitcnt vmcnt(0)" ::: "memory");
        __builtin_amdgcn_s_barrier();
        asm volatile("" ::: "memory");
    }
#undef STAGE_KT

    // ---- epilogue: lane owns one q-row; merge the two key-halves ----
    {
        float l = l_run + __shfl_xor(l_run, 32);
        float inv = 1.0f / l;
        size_t row = (tokbase + l31) * 2048 + h * 128;
#pragma unroll
        for (int db = 0; db < 4; db++)
#pragma unroll
            for (int g = 0; g < 4; g++) {
                int d = db * 32 + 8 * g + 4 * hi;
                uint2 u;
                u.x = pk_bf16(oacc[db][4 * g] * inv, oacc[db][4 * g + 1] * inv);
                u.y = pk_bf16(oacc[db][4 * g + 2] * inv, oacc[db][4 * g + 3] * inv);
                *(uint2*)(O + row + d) = u;
            }
    }
}

// ---------------- launcher ----------------
extern "C" void kernel_launch(void* const* d_in, const int* in_sizes, int n_in,
                              void* d_out, int out_size, void* d_ws, size_t ws_size,
                              hipStream_t stream) {
    const float* x  = (const float*)d_in[0];
    const float* Wq = (const float*)d_in[1];
    const float* Wk = (const float*)d_in[2];
    const float* Wv = (const float*)d_in[3];
    const float* Wo = (const float*)d_in[4];

    char* ws = (char*)d_ws;
    unsigned short* x_bf   = (unsigned short*)(ws);               // 16 MB
    unsigned short* Wqk_bf = (unsigned short*)(ws + 16777216);    // 12 MB (Wq;Wk)
    unsigned short* Wv_bf  = (unsigned short*)(ws + 29360128);    // 4 MB
    unsigned short* Wo_bf  = (unsigned short*)(ws + 33554432);    // 8 MB
    unsigned short* QKb    = (unsigned short*)(ws + 41943040);    // 24 MB (4096x3072)
    unsigned short* Vtb    = (unsigned short*)(ws + 67108864);    // 8 MB  (1024x4096)
    unsigned short* Ob     = (unsigned short*)(ws + 75497472);    // 16 MB (4096x2048)

    cast_all_kernel<<<dim3(20480), 256, 0, stream>>>(
        x, Wq, Wk, Wv, Wo, x_bf, Wqk_bf, Wv_bf, Wo_bf);

    // QK = x @ [Wq;Wk]^T  and  Vt = Wv @ x^T, merged (1024 blocks)
    gemm_qkv_kernel<<<dim3(1024), 256, 0, stream>>>(x_bf, Wqk_bf, Wv_bf, QKb, Vtb);

    // flash attention: 128 tokens/block
    flash_kernel<<<dim3(16, 32), 256, 0, stream>>>(QKb, Vtb, Ob);

    // out = O @ Wo^T : M=4096, N=2048, K=2048, fp32 out
    gemm_o_kernel<<<dim3(16, 32), 256, 0, stream>>>(Ob, Wo_bf, (float*)d_out);
}